// Round 1
// baseline (807.051 us; speedup 1.0000x reference)
//
#include <hip/hip_runtime.h>
#include <hip/hip_bf16.h>

typedef __bf16 bf16;
typedef __bf16 bf16x4 __attribute__((ext_vector_type(4)));
typedef __bf16 bf16x8 __attribute__((ext_vector_type(8)));
typedef float  f32x4  __attribute__((ext_vector_type(4)));

#define GAS __attribute__((address_space(1)))
#define LAS __attribute__((address_space(3)))

#define NROWS 4096
#define DIN   2048
#define DHID  8192
#define DOUT  2048

__device__ __forceinline__ void gload16(const void* g, void* l) {
    __builtin_amdgcn_global_load_lds((GAS void*)g, (LAS void*)l, 16, 0, 0);
}

// ---------------- Gram-Schmidt (MGS, matches reference) : 1 block, 1 wave ----
// U: 2048x8 row-major. Vt out: 8x2048 (fp32).
__global__ __launch_bounds__(64) void gs_kernel(const float* __restrict__ U,
                                                float* __restrict__ Vt) {
    __shared__ float Vs[8][DIN];
    const int l = threadIdx.x;
    float u[32];
    for (int r = 0; r < 8; ++r) {
        #pragma unroll
        for (int s = 0; s < 32; ++s) u[s] = U[(size_t)(l * 32 + s) * 8 + r];
        for (int j = 0; j < r; ++j) {
            float d = 0.f;
            #pragma unroll
            for (int s = 0; s < 32; ++s) d += Vs[j][l * 32 + s] * u[s];
            #pragma unroll
            for (int o = 32; o >= 1; o >>= 1) d += __shfl_xor(d, o);
            #pragma unroll
            for (int s = 0; s < 32; ++s) u[s] -= d * Vs[j][l * 32 + s];
        }
        float nr = 0.f;
        #pragma unroll
        for (int s = 0; s < 32; ++s) nr += u[s] * u[s];
        #pragma unroll
        for (int o = 32; o >= 1; o >>= 1) nr += __shfl_xor(nr, o);
        const float inv = 1.f / (sqrtf(nr) + 1e-6f);
        #pragma unroll
        for (int s = 0; s < 32; ++s) {
            float v = u[s] * inv;
            Vs[r][l * 32 + s] = v;
            Vt[r * DIN + l * 32 + s] = v;
        }
        __syncthreads();
    }
}

// ---------------- P = V^T @ W_random : 8 x 8192 (fp32) -----------------------
__global__ __launch_bounds__(256) void p_kernel(const float* __restrict__ W,
                                                const float* __restrict__ Vt,
                                                float* __restrict__ P) {
    const int t = threadIdx.x;
    const int c = blockIdx.x * 64 + (t & 63);
    const int part = t >> 6;
    float acc[8] = {};
    const int i0 = part * 512;
    #pragma unroll 4
    for (int i = i0; i < i0 + 512; ++i) {
        float w = W[(size_t)i * DHID + c];
        #pragma unroll
        for (int r = 0; r < 8; ++r) acc[r] = fmaf(Vt[r * DIN + i], w, acc[r]);
    }
    __shared__ float red[4][8][64];
    #pragma unroll
    for (int r = 0; r < 8; ++r) red[part][r][t & 63] = acc[r];
    __syncthreads();
    for (int idx = t; idx < 512; idx += 256) {
        int r = idx >> 6, cc = idx & 63;
        P[(size_t)r * DHID + blockIdx.x * 64 + cc] =
            red[0][r][cc] + red[1][r][cc] + red[2][r][cc] + red[3][r][cc];
    }
}

// ---------------- xV = x @ V : 4096 x 8 (fp32), one wave per row -------------
__global__ __launch_bounds__(64) void xv_kernel(const float* __restrict__ x,
                                                const float* __restrict__ Vt,
                                                float* __restrict__ xV) {
    const int row = blockIdx.x, l = threadIdx.x;
    const float* xr = x + (size_t)row * DIN;
    float acc[8] = {};
    #pragma unroll 4
    for (int s = 0; s < 32; ++s) {
        int k = s * 64 + l;
        float xv = xr[k];
        #pragma unroll
        for (int r = 0; r < 8; ++r) acc[r] = fmaf(xv, Vt[r * DIN + k], acc[r]);
    }
    #pragma unroll
    for (int r = 0; r < 8; ++r) {
        float d = acc[r];
        #pragma unroll
        for (int o = 32; o >= 1; o >>= 1) d += __shfl_xor(d, o);
        if (l == 0) xV[(size_t)row * 8 + r] = d;
    }
}

// ---------------- fp32 -> bf16 cast (same layout) ----------------------------
__global__ __launch_bounds__(256) void conv_kernel(const float* __restrict__ in,
                                                   bf16* __restrict__ out, int n4) {
    int i = blockIdx.x * 256 + threadIdx.x;
    int stride = gridDim.x * 256;
    for (; i < n4; i += stride) {
        float4 v = ((const float4*)in)[i];
        bf16x4 o = { (bf16)v.x, (bf16)v.y, (bf16)v.z, (bf16)v.w };
        *(bf16x4*)&out[(size_t)i * 4] = o;
    }
}

// ---------------- transpose + fp32->bf16 : in RxC fp32 -> out CxR bf16 -------
__global__ __launch_bounds__(256) void tconv_kernel(const float* __restrict__ in,
                                                    bf16* __restrict__ out,
                                                    int R, int C) {
    __shared__ bf16 tile[64][66];
    const int t = threadIdx.x;
    const int n0 = blockIdx.x * 64, k0 = blockIdx.y * 64;
    const int rr = t >> 4, c4 = (t & 15) * 4;
    #pragma unroll
    for (int q = 0; q < 4; ++q) {
        int row = k0 + rr + q * 16;
        float4 v = *(const float4*)&in[(size_t)row * C + n0 + c4];
        tile[c4 + 0][rr + q * 16] = (bf16)v.x;
        tile[c4 + 1][rr + q * 16] = (bf16)v.y;
        tile[c4 + 2][rr + q * 16] = (bf16)v.z;
        tile[c4 + 3][rr + q * 16] = (bf16)v.w;
    }
    __syncthreads();
    const int n = t >> 2, kk = (t & 3) * 16;
    unsigned int w[8];
    #pragma unroll
    for (int i = 0; i < 8; ++i) w[i] = *(const unsigned int*)&tile[n][kk + i * 2];
    uint4 lo = { w[0], w[1], w[2], w[3] }, hi = { w[4], w[5], w[6], w[7] };
    uint4* dst = (uint4*)&out[(size_t)(n0 + n) * R + k0 + kk];
    dst[0] = lo;
    dst[1] = hi;
}

// ---------------- bf16 GEMM (B^T input), 128x128 tile, m97 structure ---------
// C[m][n] = sum_k A[m][k]*Bt[n][k]  (+ epilogue)
// EPI==1: v = acc - 2*sum_r xV[row][r]*P[r][col]; v = gelu_exact(v); bf16 out
// EPI==0: v = acc + bias[col]; fp32 out
template <int EPI>
__global__ __launch_bounds__(256) void gemm_bt(const bf16* __restrict__ A,
                                               const bf16* __restrict__ Bt,
                                               const int M, const int N, const int K,
                                               const float* __restrict__ e0,
                                               const float* __restrict__ e1,
                                               void* __restrict__ Cout) {
    __shared__ __align__(16) bf16 Al[128 * 32];
    __shared__ __align__(16) bf16 Bl[128 * 32];
    const int t = threadIdx.x;

    // XCD-aware bijective swizzle (gridDim.x % 8 == 0 for all our launches)
    const int nwg = gridDim.x;
    const int orig = blockIdx.x;
    const int swz = (orig & 7) * (nwg >> 3) + (orig >> 3);
    const int ntn = N >> 7;
    const int bn = swz % ntn;
    const int bm = swz / ntn;

    const int wid = t >> 6, lane = t & 63;
    const int wr = wid >> 1, wc = wid & 1;
    const int lrow = lane & 15;
    const int lk = (lane >> 4) << 3;

    f32x4 acc[4][4] = {};

    const bf16* Ab = A + (size_t)bm * 128 * K;
    const bf16* Bb = Bt + (size_t)bn * 128 * K;
    const int q0 = t, q1 = t + 256;
    const int r0 = q0 >> 2, c0 = (q0 & 3) << 3;
    const int r1 = q1 >> 2, c1 = (q1 & 3) << 3;
    const unsigned lo0 = (unsigned)((t & 192) * 16);
    const unsigned lo1 = (unsigned)((256 + (t & 192)) * 16);

    const int nk = K >> 5;
    for (int kt = 0; kt < nk; ++kt) {
        __syncthreads();
        const size_t ko = (size_t)kt * 32;
        gload16(Ab + (size_t)r0 * K + ko + c0, (char*)Al + lo0);
        gload16(Ab + (size_t)r1 * K + ko + c1, (char*)Al + lo1);
        gload16(Bb + (size_t)r0 * K + ko + c0, (char*)Bl + lo0);
        gload16(Bb + (size_t)r1 * K + ko + c1, (char*)Bl + lo1);
        __syncthreads();
        bf16x8 af[4], bfr[4];
        #pragma unroll
        for (int m = 0; m < 4; ++m)
            af[m] = *(const bf16x8*)&Al[(wr * 64 + m * 16 + lrow) * 32 + lk];
        #pragma unroll
        for (int n = 0; n < 4; ++n)
            bfr[n] = *(const bf16x8*)&Bl[(wc * 64 + n * 16 + lrow) * 32 + lk];
        #pragma unroll
        for (int m = 0; m < 4; ++m)
            #pragma unroll
            for (int n = 0; n < 4; ++n)
                acc[m][n] = __builtin_amdgcn_mfma_f32_16x16x32_bf16(af[m], bfr[n], acc[m][n], 0, 0, 0);
    }
    __syncthreads();

    const int jrow = (lane >> 4) << 2;
    if (EPI == 1) {
        float* xVl = (float*)Al;  // 128 rows x 8
        float* Pl  = (float*)Bl;  // 8 x 128 cols
        for (int idx = t; idx < 1024; idx += 256)
            xVl[idx] = e0[(size_t)(bm * 128 + (idx >> 3)) * 8 + (idx & 7)];
        for (int idx = t; idx < 1024; idx += 256)
            Pl[idx] = e1[(size_t)(idx >> 7) * N + (size_t)bn * 128 + (idx & 127)];
        __syncthreads();
        bf16* outp = (bf16*)Cout;
        #pragma unroll
        for (int m = 0; m < 4; ++m)
            #pragma unroll
            for (int n = 0; n < 4; ++n)
                #pragma unroll
                for (int j = 0; j < 4; ++j) {
                    int rl = wr * 64 + m * 16 + jrow + j;
                    int cl = wc * 64 + n * 16 + lrow;
                    float v = acc[m][n][j];
                    float corr = 0.f;
                    #pragma unroll
                    for (int r = 0; r < 8; ++r)
                        corr = fmaf(xVl[rl * 8 + r], Pl[r * 128 + cl], corr);
                    v = fmaf(-2.f, corr, v);
                    v = 0.5f * v * (1.f + erff(v * 0.70710678118654752440f));
                    outp[(size_t)(bm * 128 + rl) * N + bn * 128 + cl] = (bf16)v;
                }
    } else {
        (void)e1;
        float* outp = (float*)Cout;
        #pragma unroll
        for (int m = 0; m < 4; ++m)
            #pragma unroll
            for (int n = 0; n < 4; ++n)
                #pragma unroll
                for (int j = 0; j < 4; ++j) {
                    int rl = wr * 64 + m * 16 + jrow + j;
                    int cl = wc * 64 + n * 16 + lrow;
                    outp[(size_t)(bm * 128 + rl) * N + bn * 128 + cl] =
                        acc[m][n][j] + e0[bn * 128 + cl];
                }
    }
}

extern "C" void kernel_launch(void* const* d_in, const int* in_sizes, int n_in,
                              void* d_out, int out_size, void* d_ws, size_t ws_size,
                              hipStream_t stream) {
    const float* x     = (const float*)d_in[0];
    const float* hra_u = (const float*)d_in[1];
    const float* Wr    = (const float*)d_in[2];
    const float* Wo    = (const float*)d_in[3];
    const float* bias  = (const float*)d_in[4];
    float* out = (float*)d_out;
    char* ws = (char*)d_ws;

    float* Vt  = (float*)(ws + 0);          //  64 KB : 8 x 2048
    float* P   = (float*)(ws + 65536);      // 256 KB : 8 x 8192
    float* xV  = (float*)(ws + 327680);     // 128 KB : 4096 x 8
    bf16*  xb  = (bf16*)(ws + 458752);      //  16 MB : 4096 x 2048
    bf16*  WrT = (bf16*)(ws + 17235968);    //  32 MB : 8192 x 2048
    bf16*  WoT = (bf16*)(ws + 50790400);    //  32 MB : 2048 x 8192
    bf16*  hb  = (bf16*)(ws + 84344832);    //  64 MB : 4096 x 8192

    gs_kernel<<<dim3(1), dim3(64), 0, stream>>>(hra_u, Vt);
    p_kernel<<<dim3(DHID / 64), dim3(256), 0, stream>>>(Wr, Vt, P);
    xv_kernel<<<dim3(NROWS), dim3(64), 0, stream>>>(x, Vt, xV);
    conv_kernel<<<dim3(2048), dim3(256), 0, stream>>>(x, xb, (NROWS * DIN) / 4);
    tconv_kernel<<<dim3(DHID / 64, DIN / 64), dim3(256), 0, stream>>>(Wr, WrT, DIN, DHID);
    tconv_kernel<<<dim3(DOUT / 64, DHID / 64), dim3(256), 0, stream>>>(Wo, WoT, DHID, DOUT);

    gemm_bt<1><<<dim3((NROWS / 128) * (DHID / 128)), dim3(256), 0, stream>>>(
        xb, WrT, NROWS, DHID, DIN, xV, P, (void*)hb);
    gemm_bt<0><<<dim3((NROWS / 128) * (DOUT / 128)), dim3(256), 0, stream>>>(
        hb, WoT, NROWS, DOUT, DHID, bias, nullptr, (void*)out);
}

// Round 2
// 635.598 us; speedup vs baseline: 1.2698x; 1.2698x over previous
//
#include <hip/hip_runtime.h>
#include <hip/hip_bf16.h>

typedef __bf16 bf16;
typedef __bf16 bf16x4 __attribute__((ext_vector_type(4)));
typedef __bf16 bf16x8 __attribute__((ext_vector_type(8)));
typedef float  f32x4  __attribute__((ext_vector_type(4)));

#define GAS __attribute__((address_space(1)))
#define LAS __attribute__((address_space(3)))

#define NROWS 4096
#define DIN   2048
#define DHID  8192
#define DOUT  2048

__device__ __forceinline__ void gload16(const void* g, void* l) {
    __builtin_amdgcn_global_load_lds((GAS void*)g, (LAS void*)l, 16, 0, 0);
}
template <int N> __device__ __forceinline__ void vmw() {
    asm volatile("s_waitcnt vmcnt(%0)" :: "n"(N) : "memory");
}
__device__ __forceinline__ void bsync() {
    asm volatile("" ::: "memory");
    __builtin_amdgcn_s_barrier();
    asm volatile("" ::: "memory");
}

// ---------------- Gram-Schmidt (MGS, matches reference) : 1 block, 1 wave ----
__global__ __launch_bounds__(64) void gs_kernel(const float* __restrict__ U,
                                                float* __restrict__ Vt) {
    __shared__ float Vs[8][DIN];
    const int l = threadIdx.x;
    float u[32];
    for (int r = 0; r < 8; ++r) {
        #pragma unroll
        for (int s = 0; s < 32; ++s) u[s] = U[(size_t)(l * 32 + s) * 8 + r];
        for (int j = 0; j < r; ++j) {
            float d = 0.f;
            #pragma unroll
            for (int s = 0; s < 32; ++s) d += Vs[j][l * 32 + s] * u[s];
            #pragma unroll
            for (int o = 32; o >= 1; o >>= 1) d += __shfl_xor(d, o);
            #pragma unroll
            for (int s = 0; s < 32; ++s) u[s] -= d * Vs[j][l * 32 + s];
        }
        float nr = 0.f;
        #pragma unroll
        for (int s = 0; s < 32; ++s) nr += u[s] * u[s];
        #pragma unroll
        for (int o = 32; o >= 1; o >>= 1) nr += __shfl_xor(nr, o);
        const float inv = 1.f / (sqrtf(nr) + 1e-6f);
        #pragma unroll
        for (int s = 0; s < 32; ++s) {
            float v = u[s] * inv;
            Vs[r][l * 32 + s] = v;
            Vt[r * DIN + l * 32 + s] = v;
        }
        __syncthreads();
    }
}

// ---------------- P = V^T @ W_random : 8 x 8192 (fp32) -----------------------
__global__ __launch_bounds__(256) void p_kernel(const float* __restrict__ W,
                                                const float* __restrict__ Vt,
                                                float* __restrict__ P) {
    const int t = threadIdx.x;
    const int c = blockIdx.x * 64 + (t & 63);
    const int part = t >> 6;
    float acc[8] = {};
    const int i0 = part * 512;
    #pragma unroll 4
    for (int i = i0; i < i0 + 512; ++i) {
        float w = W[(size_t)i * DHID + c];
        #pragma unroll
        for (int r = 0; r < 8; ++r) acc[r] = fmaf(Vt[r * DIN + i], w, acc[r]);
    }
    __shared__ float red[4][8][64];
    #pragma unroll
    for (int r = 0; r < 8; ++r) red[part][r][t & 63] = acc[r];
    __syncthreads();
    for (int idx = t; idx < 512; idx += 256) {
        int r = idx >> 6, cc = idx & 63;
        P[(size_t)r * DHID + blockIdx.x * 64 + cc] =
            red[0][r][cc] + red[1][r][cc] + red[2][r][cc] + red[3][r][cc];
    }
}

// ---------------- xV = x @ V : 4096 x 8 (fp32), one wave per row -------------
__global__ __launch_bounds__(64) void xv_kernel(const float* __restrict__ x,
                                                const float* __restrict__ Vt,
                                                float* __restrict__ xV) {
    const int row = blockIdx.x, l = threadIdx.x;
    const float* xr = x + (size_t)row * DIN;
    float acc[8] = {};
    #pragma unroll 4
    for (int s = 0; s < 32; ++s) {
        int k = s * 64 + l;
        float xv = xr[k];
        #pragma unroll
        for (int r = 0; r < 8; ++r) acc[r] = fmaf(xv, Vt[r * DIN + k], acc[r]);
    }
    #pragma unroll
    for (int r = 0; r < 8; ++r) {
        float d = acc[r];
        #pragma unroll
        for (int o = 32; o >= 1; o >>= 1) d += __shfl_xor(d, o);
        if (l == 0) xV[(size_t)row * 8 + r] = d;
    }
}

// ---------------- fp32 -> bf16 cast (same layout) ----------------------------
__global__ __launch_bounds__(256) void conv_kernel(const float* __restrict__ in,
                                                   bf16* __restrict__ out, int n4) {
    int i = blockIdx.x * 256 + threadIdx.x;
    int stride = gridDim.x * 256;
    for (; i < n4; i += stride) {
        float4 v = ((const float4*)in)[i];
        bf16x4 o = { (bf16)v.x, (bf16)v.y, (bf16)v.z, (bf16)v.w };
        *(bf16x4*)&out[(size_t)i * 4] = o;
    }
}

// ---------------- transpose + fp32->bf16 : in RxC fp32 -> out CxR bf16 -------
__global__ __launch_bounds__(256) void tconv_kernel(const float* __restrict__ in,
                                                    bf16* __restrict__ out,
                                                    int R, int C) {
    __shared__ bf16 tile[64][66];
    const int t = threadIdx.x;
    const int n0 = blockIdx.x * 64, k0 = blockIdx.y * 64;
    const int rr = t >> 4, c4 = (t & 15) * 4;
    #pragma unroll
    for (int q = 0; q < 4; ++q) {
        int row = k0 + rr + q * 16;
        float4 v = *(const float4*)&in[(size_t)row * C + n0 + c4];
        tile[c4 + 0][rr + q * 16] = (bf16)v.x;
        tile[c4 + 1][rr + q * 16] = (bf16)v.y;
        tile[c4 + 2][rr + q * 16] = (bf16)v.z;
        tile[c4 + 3][rr + q * 16] = (bf16)v.w;
    }
    __syncthreads();
    const int n = t >> 2, kk = (t & 3) * 16;
    unsigned int w[8];
    #pragma unroll
    for (int i = 0; i < 8; ++i) w[i] = *(const unsigned int*)&tile[n][kk + i * 2];
    uint4 lo = { w[0], w[1], w[2], w[3] }, hi = { w[4], w[5], w[6], w[7] };
    uint4* dst = (uint4*)&out[(size_t)(n0 + n) * R + k0 + kk];
    dst[0] = lo;
    dst[1] = hi;
}

// ---------------- bf16 GEMM, BK=32, 4-deep LDS ring, counted vmcnt -----------
// C = A @ Bt^T. 512 threads = 8 waves (WM x WN), wave tile (BM/WM) x (BN/WN).
// LDS swizzle (involution, 16B granular): byte ^= ((row>>1)&3)<<4 for 64B rows.
// Staged via global_load_lds with inverse-swizzled SOURCE (rule #21).
// XCD chunking: xcd = bid&7 owns a CR x CC rectangle of output tiles.
template <int BM, int BN, int WM, int WN, int CR, int CC, int EPI>
__global__ __launch_bounds__(512) void gemm256(const bf16* __restrict__ A,
                                               const bf16* __restrict__ Bt,
                                               const int N, const int K,
                                               const float* __restrict__ e0,
                                               const float* __restrict__ e1,
                                               void* __restrict__ Cout) {
    constexpr int MF = BM / (WM * 16);
    constexpr int NF = BN / (WN * 16);
    constexpr int ABYTES = BM * 64;          // A region bytes per buffer (32k x 2B)
    constexpr int BUFB = (BM + BN) * 64;     // bytes per ring slot
    constexpr int LA = BM / 128, LB = BN / 128, LPT = LA + LB;
    __shared__ __align__(128) char lds[4 * BUFB];

    const int t = threadIdx.x;
    const int wid = t >> 6, lane = t & 63;
    const int wr = wid / WN, wc = wid % WN;
    const int lrow = lane & 15;
    const int lk2 = (lane >> 4) * 16;        // byte offset of k-group

    const int chunks_c = (N / BN) / CC;
    const int xc = blockIdx.x & 7;
    const int ii = blockIdx.x >> 3;
    const int bm = (xc / chunks_c) * CR + ii / CC;
    const int bn = (xc % chunks_c) * CC + ii % CC;

    const bf16* Abase = A + (size_t)bm * BM * K;
    const bf16* Bbase = Bt + (size_t)bn * BN * K;

    // swizzled ds_read byte offsets (key invariant across m*16 row steps)
    const int ar0 = wr * (MF * 16) + lrow;
    const unsigned aoff = (unsigned)(ar0 * 64 + lk2) ^ (unsigned)(((ar0 >> 1) & 3) << 4);
    const int br0 = wc * (NF * 16) + lrow;
    const unsigned boff = (unsigned)ABYTES +
        ((unsigned)(br0 * 64 + lk2) ^ (unsigned)(((br0 >> 1) & 3) << 4));

    f32x4 acc[MF][NF] = {};

    auto STAGE = [&](int kt, int b) {
        const size_t ko = (size_t)kt * 32;
        char* dstb = lds + b * BUFB;
        #pragma unroll
        for (int i2 = 0; i2 < LA; ++i2) {
            const int lin = i2 * 512 + t;
            const int row = lin >> 2;
            const int c16 = (lin & 3) ^ ((lin >> 3) & 3);   // inverse-swizzled src
            gload16(Abase + (size_t)row * K + ko + c16 * 8,
                    dstb + (i2 * 512 + (t & 448)) * 16);
        }
        #pragma unroll
        for (int i2 = 0; i2 < LB; ++i2) {
            const int lin = i2 * 512 + t;
            const int row = lin >> 2;
            const int c16 = (lin & 3) ^ ((lin >> 3) & 3);
            gload16(Bbase + (size_t)row * K + ko + c16 * 8,
                    dstb + ABYTES + (i2 * 512 + (t & 448)) * 16);
        }
    };

    auto COMPUTE = [&](int b) {
        const char* bp = lds + b * BUFB;
        bf16x8 af[MF], bv[NF];
        #pragma unroll
        for (int m = 0; m < MF; ++m) af[m] = *(const bf16x8*)(bp + aoff + m * 1024);
        #pragma unroll
        for (int n = 0; n < NF; ++n) bv[n] = *(const bf16x8*)(bp + boff + n * 1024);
        __builtin_amdgcn_s_setprio(1);
        #pragma unroll
        for (int m = 0; m < MF; ++m)
            #pragma unroll
            for (int n = 0; n < NF; ++n)
                acc[m][n] = __builtin_amdgcn_mfma_f32_16x16x32_bf16(af[m], bv[n], acc[m][n], 0, 0, 0);
        __builtin_amdgcn_s_setprio(0);
    };

    const int nk = K >> 5;
    STAGE(0, 0); STAGE(1, 1); STAGE(2, 2);
    int kt = 0;
    for (; kt < nk - 3; ++kt) {
        STAGE(kt + 3, (kt + 3) & 3);
        vmw<3 * LPT>();                 // tile kt landed; 3 tiles stay in flight
        bsync();
        COMPUTE(kt & 3);
        bsync();
    }
    vmw<2 * LPT>(); bsync(); COMPUTE(kt & 3); bsync(); ++kt;
    vmw<1 * LPT>(); bsync(); COMPUTE(kt & 3); bsync(); ++kt;
    vmw<0>();       bsync(); COMPUTE(kt & 3); bsync();

    const int jrow = (lane >> 4) << 2;
    if (EPI == 1) {
        float* xVl = (float*)lds;                 // BM x 8
        float* Pl  = (float*)(lds + BM * 32);     // 8 x BN
        for (int idx = t; idx < BM * 8; idx += 512)
            xVl[idx] = e0[((size_t)bm * BM + (idx >> 3)) * 8 + (idx & 7)];
        for (int idx = t; idx < BN * 8; idx += 512)
            Pl[idx] = e1[(size_t)(idx / BN) * N + (size_t)bn * BN + (idx % BN)];
        bsync();
        bf16* outp = (bf16*)Cout;
        #pragma unroll
        for (int m = 0; m < MF; ++m)
            #pragma unroll
            for (int n = 0; n < NF; ++n)
                #pragma unroll
                for (int j = 0; j < 4; ++j) {
                    const int rl = wr * (MF * 16) + m * 16 + jrow + j;
                    const int cl = wc * (NF * 16) + n * 16 + lrow;
                    float v = acc[m][n][j];
                    float corr = 0.f;
                    #pragma unroll
                    for (int r = 0; r < 8; ++r)
                        corr = fmaf(xVl[rl * 8 + r], Pl[r * BN + cl], corr);
                    v = fmaf(-2.f, corr, v);
                    v = 0.5f * v * (1.f + erff(v * 0.70710678118654752440f));
                    outp[((size_t)bm * BM + rl) * N + bn * BN + cl] = (bf16)v;
                }
    } else {
        float* outp = (float*)Cout;
        #pragma unroll
        for (int m = 0; m < MF; ++m)
            #pragma unroll
            for (int n = 0; n < NF; ++n)
                #pragma unroll
                for (int j = 0; j < 4; ++j) {
                    const int rl = wr * (MF * 16) + m * 16 + jrow + j;
                    const int cl = wc * (NF * 16) + n * 16 + lrow;
                    outp[((size_t)bm * BM + rl) * N + bn * BN + cl] =
                        acc[m][n][j] + e0[bn * BN + cl];
                }
    }
}

extern "C" void kernel_launch(void* const* d_in, const int* in_sizes, int n_in,
                              void* d_out, int out_size, void* d_ws, size_t ws_size,
                              hipStream_t stream) {
    const float* x     = (const float*)d_in[0];
    const float* hra_u = (const float*)d_in[1];
    const float* Wr    = (const float*)d_in[2];
    const float* Wo    = (const float*)d_in[3];
    const float* bias  = (const float*)d_in[4];
    float* out = (float*)d_out;
    char* ws = (char*)d_ws;

    float* Vt  = (float*)(ws + 0);          //  64 KB : 8 x 2048
    float* P   = (float*)(ws + 65536);      // 256 KB : 8 x 8192
    float* xV  = (float*)(ws + 327680);     // 128 KB : 4096 x 8
    bf16*  xb  = (bf16*)(ws + 458752);      //  16 MB : 4096 x 2048
    bf16*  WrT = (bf16*)(ws + 17235968);    //  32 MB : 8192 x 2048
    bf16*  WoT = (bf16*)(ws + 50790400);    //  32 MB : 2048 x 8192
    bf16*  hb  = (bf16*)(ws + 84344832);    //  64 MB : 4096 x 8192

    gs_kernel<<<dim3(1), dim3(64), 0, stream>>>(hra_u, Vt);
    p_kernel<<<dim3(DHID / 64), dim3(256), 0, stream>>>(Wr, Vt, P);
    xv_kernel<<<dim3(NROWS), dim3(64), 0, stream>>>(x, Vt, xV);
    conv_kernel<<<dim3(2048), dim3(256), 0, stream>>>(x, xb, (NROWS * DIN) / 4);
    tconv_kernel<<<dim3(DHID / 64, DIN / 64), dim3(256), 0, stream>>>(Wr, WrT, DIN, DHID);
    tconv_kernel<<<dim3(DOUT / 64, DHID / 64), dim3(256), 0, stream>>>(Wo, WoT, DHID, DOUT);

    // GEMM1: 4096x8192x2048, tiles 16x32=512 blocks, XCD chunk 8x8
    gemm256<256, 256, 2, 4, 8, 8, 1><<<dim3(512), dim3(512), 0, stream>>>(
        xb, WrT, DHID, DIN, xV, P, (void*)hb);
    // GEMM2: 4096x2048x8192, tiles 16x16=256 blocks, XCD chunk 4x8
    gemm256<256, 128, 4, 2, 4, 8, 0><<<dim3(256), dim3(512), 0, stream>>>(
        hb, WoT, DOUT, DHID, bias, nullptr, (void*)out);
}